// Round 13
// baseline (584.669 us; speedup 1.0000x reference)
//
#include <hip/hip_runtime.h>

#define CN 2000
#define DF 2048
#define NS 20000
#define NBLK 125
#define NGRP 25
#define GRPSZ 5

typedef __attribute__((ext_vector_type(4))) float          f32x4;
typedef __attribute__((ext_vector_type(4))) int            i32x4;
typedef __attribute__((ext_vector_type(4))) unsigned short u16x4;

__device__ __forceinline__ float wredSum(float v){
#pragma unroll
  for (int o = 32; o >= 1; o >>= 1) v += __shfl_xor(v, o, 64);
  return v;
}
__device__ __forceinline__ float wredMax(float v){
#pragma unroll
  for (int o = 32; o >= 1; o >>= 1) v = fmaxf(v, __shfl_xor(v, o, 64));
  return v;
}
__device__ __forceinline__ unsigned short bfbits(float x){
  union { float f; unsigned u; } c; c.f = x;
  return (unsigned short)((c.u + 0x7fffu + ((c.u >> 16) & 1u)) >> 16);
}
__device__ __forceinline__ void gload16(const void* g, void* lds){
  __builtin_amdgcn_global_load_lds((const __attribute__((address_space(1))) unsigned int*)g,
      (__attribute__((address_space(3))) unsigned int*)lds, 16, 0, 0);
}

// Fence-free monotonic hierarchical grid barrier (agent-scope atomics only).
// bar[0]=root, bar[32]=generation, bar[64+g*32]=group counters. The leading
// s_waitcnt vmcnt(0) drains each thread's own stores before arrival.
__device__ __forceinline__ void gbar(int* bar, int target){
  asm volatile("s_waitcnt vmcnt(0)" ::: "memory");
  __syncthreads();
  if (threadIdx.x == 0){
    int g = blockIdx.x / GRPSZ;
    int prev = __hip_atomic_fetch_add(&bar[64 + g * 32], 1,
                  __ATOMIC_RELAXED, __HIP_MEMORY_SCOPE_AGENT);
    if (prev == target * GRPSZ - 1){
      int rp = __hip_atomic_fetch_add(&bar[0], 1,
                  __ATOMIC_RELAXED, __HIP_MEMORY_SCOPE_AGENT);
      if (rp == target * NGRP - 1){
        __hip_atomic_store(&bar[32], target, __ATOMIC_RELAXED, __HIP_MEMORY_SCOPE_AGENT);
      }
    }
    while (__hip_atomic_load(&bar[32], __ATOMIC_RELAXED, __HIP_MEMORY_SCOPE_AGENT) < target){
      __builtin_amdgcn_s_sleep(1);
    }
  }
  __syncthreads();
}

__global__ void k_zero(int* p, int n, int* bar){
  int i = blockIdx.x * 256 + threadIdx.x;
  if (i < n) p[i] = 0;
  if (i < 1024) bar[i] = 0;
}

__global__ void k_hist(const int* __restrict__ rgb, const int* __restrict__ iri,
                       int* cv, int* ci){
  int i = blockIdx.x * 256 + threadIdx.x;
  if (i < NS) atomicAdd(&cv[rgb[i]], 1);
  else if (i < 2 * NS) atomicAdd(&ci[iri[i - NS]], 1);
}

__global__ __launch_bounds__(1024) void k_scan(const int* __restrict__ cv, const int* __restrict__ ci,
                                               int* ov, int* oi){
  __shared__ int s[2048];
  int t = threadIdx.x;
  for (int pass = 0; pass < 2; ++pass){
    const int* c = pass ? ci : cv;
    int* o = pass ? oi : ov;
    s[t] = (t < CN) ? c[t] : 0;
    s[t + 1024] = (t + 1024 < CN) ? c[t + 1024] : 0;
    __syncthreads();
    for (int off = 1; off < 2048; off <<= 1){
      int a = (t >= off) ? s[t - off] : 0;
      int b = (t + 1024 >= off) ? s[t + 1024 - off] : 0;
      __syncthreads();
      s[t] += a; s[t + 1024] += b;
      __syncthreads();
    }
    if (t < CN) o[t] = s[t] - c[t];
    if (t + 1024 < CN) o[t + 1024] = s[t + 1024] - c[t + 1024];
    __syncthreads();
  }
}

__global__ void k_scatter(const int* __restrict__ rgb, const int* __restrict__ iri,
                          const int* __restrict__ ov, const int* __restrict__ oi,
                          int* curv, int* curi, int* ordv, int* ordi){
  int i = blockIdx.x * 256 + threadIdx.x;
  if (i < NS){
    int l = rgb[i];
    int p = atomicAdd(&curv[l], 1);
    ordv[ov[l] + p] = i;
  } else if (i < 2 * NS){
    int k = i - NS;
    int l = iri[k];
    int p = atomicAdd(&curi[l], 1);
    ordi[oi[l] + p] = k;
  }
}

// Blocks [0, 2*CN): one block per (modality,class) — softmax+proto+entropy.
// Blocks [2*CN, 2*CN+1000): f32->bf16 conversion + row-norm.
// vmb/imb live in o5/o1 (dead until k_sink-fill / k_tr).
__global__ __launch_bounds__(256) void k_class(const float* __restrict__ visl, const float* __restrict__ irl,
    const int* __restrict__ cv, const int* __restrict__ ci,
    const int* __restrict__ ov, const int* __restrict__ oi,
    const int* __restrict__ ordv, const int* __restrict__ ordi,
    float* __restrict__ pv, float* __restrict__ pi_,
    float* __restrict__ ev, float* __restrict__ ei,
    const float* __restrict__ vm, const float* __restrict__ im,
    unsigned short* __restrict__ vmb, unsigned short* __restrict__ imb,
    float* __restrict__ rv, float* __restrict__ ri){
  if (blockIdx.x >= 2 * CN){
    int g = (blockIdx.x - 2 * CN) * 256 + threadIdx.x;
    int wid = g >> 6, l = g & 63;
    if (wid >= 2 * CN) return;
    const float* src = (wid < CN) ? vm : im;
    unsigned short* dst = (wid < CN) ? vmb : imb;
    int r = (wid < CN) ? wid : wid - CN;
    const f32x4* row = (const f32x4*)(src + (size_t)r * DF);
    float s = 0.f;
#pragma unroll
    for (int k = 0; k < 8; ++k){
      int idx = l + k * 64;
      f32x4 vv = row[idx];
      s += vv[0]*vv[0] + vv[1]*vv[1] + vv[2]*vv[2] + vv[3]*vv[3];
      u16x4 o;
      o[0] = bfbits(vv[0]); o[1] = bfbits(vv[1]); o[2] = bfbits(vv[2]); o[3] = bfbits(vv[3]);
      *(u16x4*)(dst + (size_t)r * DF + idx * 4) = o;
    }
    s = wredSum(s);
    if (l == 0) ((wid < CN) ? rv : ri)[r] = 1.f / fmaxf(sqrtf(s), 1e-12f);
    return;
  }
  __shared__ __attribute__((aligned(16))) float acc4[4][2048];
  __shared__ int mem[128];
  __shared__ float red[4];
  int t = threadIdx.x, w = t >> 6, l = t & 63;
  bool ir = (blockIdx.x >= CN);
  int c = ir ? blockIdx.x - CN : blockIdx.x;
  const float* logits = ir ? irl : visl;
  int n = (ir ? ci : cv)[c];
  int base = (ir ? oi : ov)[c];
  const int* ord = ir ? ordi : ordv;
  float* proto = ir ? pi_ : pv;
  float* ent = ir ? ei : ev;
  bool useL = (n <= 128);
  for (int m = t; m < n && m < 128; m += 256) mem[m] = ord[base + m];
  for (int j = t; j < 2048; j += 256){
    acc4[0][j] = 0.f; acc4[1][j] = 0.f; acc4[2][j] = 0.f; acc4[3][j] = 0.f;
  }
  __syncthreads();
  if (t == 0 && useL){  // deterministic member order across replays
    for (int a = 1; a < n; ++a){
      int key = mem[a]; int b = a - 1;
      while (b >= 0 && mem[b] > key){ mem[b + 1] = mem[b]; --b; }
      mem[b + 1] = key;
    }
  }
  __syncthreads();
  for (int m = w; m < n; m += 4){
    int sidx = useL ? mem[m] : ord[base + m];
    const f32x4* row = (const f32x4*)(logits + (size_t)sidx * CN);
    f32x4 x[8]; float mx = -3.0e38f;
#pragma unroll
    for (int k = 0; k < 8; ++k){
      int idx = l + k * 64;
      f32x4 vv = {-3.0e38f, -3.0e38f, -3.0e38f, -3.0e38f};
      if (idx < 500) vv = row[idx];
      x[k] = vv;
      mx = fmaxf(mx, fmaxf(fmaxf(vv[0], vv[1]), fmaxf(vv[2], vv[3])));
    }
    mx = wredMax(mx);
    float sm = 0.f;
#pragma unroll
    for (int k = 0; k < 8; ++k){
      int idx = l + k * 64;
      if (idx < 500){
        f32x4 e;
        e[0] = expf(x[k][0] - mx); e[1] = expf(x[k][1] - mx);
        e[2] = expf(x[k][2] - mx); e[3] = expf(x[k][3] - mx);
        x[k] = e;
        sm += e[0] + e[1] + e[2] + e[3];
      }
    }
    sm = wredSum(sm);
    float inv = 1.f / sm;
#pragma unroll
    for (int k = 0; k < 8; ++k){
      int idx = l + k * 64;
      if (idx < 500){
        f32x4* a = (f32x4*)&acc4[w][idx * 4];
        f32x4 cur = *a;
        cur[0] += x[k][0] * inv; cur[1] += x[k][1] * inv;
        cur[2] += x[k][2] * inv; cur[3] += x[k][3] * inv;
        *a = cur;
      }
    }
  }
  __syncthreads();
  float invc = 1.f / fmaxf((float)n, 1.f);
  float el = 0.f;
  for (int j = t; j < CN; j += 256){
    float p = (acc4[0][j] + acc4[1][j] + acc4[2][j] + acc4[3][j]) * invc;
    proto[(size_t)c * CN + j] = p;
    p = fmaxf(p, 1e-12f);
    el -= p * logf(p);
  }
  el = wredSum(el);
  if (l == 0) red[w] = el;
  __syncthreads();
  if (t == 0) ent[c] = red[0] + red[1] + red[2] + red[3];
}

// E[i][j] = active ? exp(-(0.45*(1-pred) + 0.15*(1-conf))/0.07) : 0
__global__ __launch_bounds__(256) void k_prep(const float* __restrict__ pv, const float* __restrict__ pi_,
    const float* __restrict__ ev, const float* __restrict__ ei,
    const int* __restrict__ cv, const int* __restrict__ ci, float* __restrict__ E){
  __shared__ float s[64][65];
  int t = threadIdx.x;
  int i0 = blockIdx.y * 64, j0 = blockIdx.x * 64;
#pragma unroll
  for (int rr = 0; rr < 4; ++rr){
    int jl = (t >> 4) + rr * 16;
    int ch = t & 15;
    int gj = j0 + jl;
    int gib = i0 + ch * 4;
    f32x4 vv = {0.f, 0.f, 0.f, 0.f};
    if (gj < CN){
      if (gib + 3 < CN) vv = *(const f32x4*)(pi_ + (size_t)gj * CN + gib);
      else {
        for (int q = 0; q < 4; ++q) if (gib + q < CN) vv[q] = pi_[(size_t)gj * CN + gib + q];
      }
    }
    s[ch*4+0][jl] = vv[0]; s[ch*4+1][jl] = vv[1]; s[ch*4+2][jl] = vv[2]; s[ch*4+3][jl] = vv[3];
  }
  __syncthreads();
#pragma unroll
  for (int rr = 0; rr < 4; ++rr){
    int il = (t >> 4) + rr * 16;
    int ch = t & 15;
    int gi = i0 + il;
    int gjb = j0 + ch * 4;
    if (gi >= CN) continue;
    f32x4 pvv = {0.f, 0.f, 0.f, 0.f};
    bool full = (gjb + 3 < CN);
    if (full) pvv = *(const f32x4*)(pv + (size_t)gi * CN + gjb);
    else { for (int q = 0; q < 4; ++q) if (gjb + q < CN) pvv[q] = pv[(size_t)gi * CN + gjb + q]; }
    float evi = ev[gi];
    bool avi = cv[gi] > 0;
    f32x4 o;
#pragma unroll
    for (int q = 0; q < 4; ++q){
      int gj = gjb + q;
      if (gj >= CN){ o[q] = 0.f; continue; }
      float pred = 0.5f * (pvv[q] + s[il][ch*4+q]);
      float conf = fminf(fmaxf(1.f - (evi + ei[gj]) / 15.201804919084164f, 0.f), 1.f);
      float base = 0.45f * (1.f - pred) + 0.15f * (1.f - conf);
      bool act = avi && (ci[gj] > 0);
      o[q] = act ? expf(-base / 0.07f) : 0.f;
    }
    if (full) *(f32x4*)(E + (size_t)gi * CN + gjb) = o;
    else { for (int q = 0; q < 4; ++q) if (gjb + q < CN) E[(size_t)gi * CN + gjb + q] = o[q]; }
  }
}

// bf16 MFMA GEMM, 128x128 tile, BK=64, global_load_lds staging with XOR
// swizzle + XCD-aware block swizzle (256 wgs, bijective).
__global__ __launch_bounds__(256) void k_gemm2(const unsigned short* __restrict__ Ag,
    const unsigned short* __restrict__ Bg, const float* __restrict__ rv,
    const float* __restrict__ ri, const float* __restrict__ E, float* __restrict__ Km){
  __shared__ __attribute__((aligned(16))) unsigned short As[128 * 64];
  __shared__ __attribute__((aligned(16))) unsigned short Bs[128 * 64];
  int t = threadIdx.x, w = t >> 6, l = t & 63;
  int bid = blockIdx.y * 16 + blockIdx.x;
  int swz = (bid & 7) * 32 + (bid >> 3);
  int i0 = (swz >> 4) * 128, j0 = (swz & 15) * 128;
  int wm = w >> 1, wn = w & 1;
  int srow8 = l >> 3, sch = l & 7;
  int lr = l & 15, hk = l >> 4;
  f32x4 z = {0.f, 0.f, 0.f, 0.f};
  f32x4 acc[4][4];
#pragma unroll
  for (int a = 0; a < 4; ++a)
#pragma unroll
    for (int b = 0; b < 4; ++b) acc[a][b] = z;

  for (int kt = 0; kt < DF / 64; ++kt){
    int k0 = kt * 64;
#pragma unroll
    for (int c2 = 0; c2 < 4; ++c2){
      int rbase = c2 * 32 + w * 8;
      int row = rbase + srow8;
      int lch = sch ^ (srow8 & 7);
      int gi = i0 + row; if (gi > CN - 1) gi = CN - 1;
      int gj = j0 + row; if (gj > CN - 1) gj = CN - 1;
      gload16(Ag + (size_t)gi * DF + k0 + lch * 8, &As[rbase * 64]);
      gload16(Bg + (size_t)gj * DF + k0 + lch * 8, &Bs[rbase * 64]);
    }
    __syncthreads();
#pragma unroll
    for (int s2 = 0; s2 < 2; ++s2){
      i32x4 af[4], bf[4];
#pragma unroll
      for (int f2 = 0; f2 < 4; ++f2){
        int ar = wm * 64 + f2 * 16 + lr;
        int ac = (s2 * 4 + hk) ^ (ar & 7);
        af[f2] = *(const i32x4*)&As[ar * 64 + ac * 8];
        int br = wn * 64 + f2 * 16 + lr;
        int bc = (s2 * 4 + hk) ^ (br & 7);
        bf[f2] = *(const i32x4*)&Bs[br * 64 + bc * 8];
      }
#pragma unroll
      for (int a = 0; a < 4; ++a)
#pragma unroll
        for (int b = 0; b < 4; ++b)
          asm volatile("v_mfma_f32_16x16x32_bf16 %0, %1, %2, %0"
                       : "+v"(acc[a][b]) : "v"(af[a]), "v"(bf[b]));
    }
    __syncthreads();
  }
#pragma unroll
  for (int a = 0; a < 4; ++a){
    int ib = i0 + wm * 64 + a * 16 + hk * 4;
#pragma unroll
    for (int b = 0; b < 4; ++b){
      int j = j0 + wn * 64 + b * 16 + lr;
      if (j < CN){
        float rij = ri[j];
#pragma unroll
        for (int q = 0; q < 4; ++q){
          int i = ib + q;
          if (i < CN){
            float dot = acc[a][b][q] * rv[i] * rij;
            float feat = fminf(fmaxf((dot + 1.f) * 0.5f, 0.f), 1.f);
            float kv = E[(size_t)i * CN + j] * expf(-0.4f * (1.f - feat) / 0.07f);
            Km[(size_t)i * CN + j] = kv;
          }
        }
      }
    }
  }
}

// 64x64 LDS transpose: KT = Km^T (overwrites imb — safe, gemm2 already done)
__global__ __launch_bounds__(256) void k_tr(const float* __restrict__ Km, float* __restrict__ KT){
  __shared__ float s[64][65];
  int t = threadIdx.x;
  int i0 = blockIdx.y * 64, j0 = blockIdx.x * 64;
#pragma unroll
  for (int rr = 0; rr < 4; ++rr){
    int il = (t >> 4) + rr * 16;
    int ch = t & 15;
    int gi = i0 + il, gjb = j0 + ch * 4;
    f32x4 vv = {0.f, 0.f, 0.f, 0.f};
    if (gi < CN){
      if (gjb + 3 < CN) vv = *(const f32x4*)(Km + (size_t)gi * CN + gjb);
      else { for (int q = 0; q < 4; ++q) if (gjb + q < CN) vv[q] = Km[(size_t)gi * CN + gjb + q]; }
    }
    s[ch*4+0][il] = vv[0]; s[ch*4+1][il] = vv[1]; s[ch*4+2][il] = vv[2]; s[ch*4+3][il] = vv[3];
  }
  __syncthreads();
#pragma unroll
  for (int rr = 0; rr < 4; ++rr){
    int jl = (t >> 4) + rr * 16;
    int ch = t & 15;
    int gj = j0 + jl, gib = i0 + ch * 4;
    if (gj >= CN) continue;
    f32x4 o;
    o[0] = s[jl][ch*4+0]; o[1] = s[jl][ch*4+1]; o[2] = s[jl][ch*4+2]; o[3] = s[jl][ch*4+3];
    if (gib + 3 < CN) *(f32x4*)(KT + (size_t)gj * CN + gib) = o;
    else { for (int q = 0; q < 4; ++q) if (gib + q < CN) KT[(size_t)gj * CN + gib + q] = o[q]; }
  }
}

#define STAGE(G, L) do { \
  float tmp_[4]; \
  _Pragma("unroll") \
  for (int k_ = 0; k_ < 4; ++k_){ \
    int idx_ = t + k_ * 512; \
    tmp_[k_] = (idx_ < CN) ? __hip_atomic_load(&(G)[idx_], __ATOMIC_RELAXED, __HIP_MEMORY_SCOPE_AGENT) : 0.f; \
  } \
  _Pragma("unroll") \
  for (int k_ = 0; k_ < 4; ++k_){ int idx_ = t + k_ * 512; if (idx_ < CN) (L)[idx_] = tmp_[k_]; } \
} while(0)

// insert candidate (cv,cj) into descending top-3 (ties -> smaller index)
#define INS3(V0,V1,V2,I0,I1,I2,cvx,cjx) do { \
  float cv_ = (cvx); int cj_ = (cjx); \
  if (cv_ > V0 || (cv_ == V0 && cj_ < I0)){ V2=V1;I2=I1; V1=V0;I1=I0; V0=cv_;I0=cj_; } \
  else if (cv_ > V1 || (cv_ == V1 && cj_ < I1)){ V2=V1;I2=I1; V1=cv_;I1=cj_; } \
  else if (cv_ > V2 || (cv_ == V2 && cj_ < I2)){ V2=cv_;I2=cj_; } \
} while(0)

// Persistent Sinkhorn: 125 blocks x 512 (16 rows/block, 2 rows/wave x 8
// waves), fence-free hierarchical barriers, coalesced LDS staging of u/v.
// FUSED epilogue: row_t/col_t writes, per-row top-3 (butterfly), cass
// publication + 1 barrier for the mutual check, then o2..o5 fill from regs.
__global__ __launch_bounds__(512, 1) void k_sink(
    const float* __restrict__ Km, const float* __restrict__ KTm,
    const int* __restrict__ cv, const int* __restrict__ ci,
    float* __restrict__ u_g, float* __restrict__ v_g,
    float* __restrict__ o0, float* __restrict__ o1,
    int* __restrict__ cass, int* bar,
    float* o2, float* o3, float* o4, float* o5){
  __shared__ __attribute__((aligned(16))) float u_lds[2048];
  __shared__ __attribute__((aligned(16))) float v_lds[2048];
  int b = blockIdx.x, t = threadIdx.x, w = t >> 6, l = t & 63;
  int r0 = b * 16 + w * 2, r1 = r0 + 1;
  f32x4 z4 = {0.f, 0.f, 0.f, 0.f};
  f32x4 kA0[8], kA1[8], kT0[8], kT1[8];
  {
    const f32x4* g0 = (const f32x4*)(Km + (size_t)r0 * CN);
    const f32x4* g1 = (const f32x4*)(Km + (size_t)r1 * CN);
    const f32x4* h0 = (const f32x4*)(KTm + (size_t)r0 * CN);
    const f32x4* h1 = (const f32x4*)(KTm + (size_t)r1 * CN);
#pragma unroll
    for (int k = 0; k < 8; ++k){
      int idx = l + k * 64;
      bool ok = idx < 500;
      kA0[k] = ok ? g0[idx] : z4;
      kA1[k] = ok ? g1[idx] : z4;
      kT0[k] = ok ? h0[idx] : z4;
      kT1[k] = ok ? h1[idx] : z4;
    }
  }
  float a0 = (float)cv[r0] / 20000.0f, a1 = (float)cv[r1] / 20000.0f;
  float b0 = (float)ci[r0] / 20000.0f, b1 = (float)ci[r1] / 20000.0f;

  // iteration 0 u-update: v === 1, so Kv = rowsum(K)
  {
    float s0 = 0.f, s1 = 0.f;
#pragma unroll
    for (int k = 0; k < 8; ++k){
      s0 += kA0[k][0] + kA0[k][1] + kA0[k][2] + kA0[k][3];
      s1 += kA1[k][0] + kA1[k][1] + kA1[k][2] + kA1[k][3];
    }
    s0 = wredSum(s0); s1 = wredSum(s1);
    if (l == 0){
      __hip_atomic_store(&u_g[r0], (a0 > 0.f) ? a0 / (s0 + 1e-8f) : 0.f,
                         __ATOMIC_RELAXED, __HIP_MEMORY_SCOPE_AGENT);
      __hip_atomic_store(&u_g[r1], (a1 > 0.f) ? a1 / (s1 + 1e-8f) : 0.f,
                         __ATOMIC_RELAXED, __HIP_MEMORY_SCOPE_AGENT);
    }
  }
  int tgt = 1;
  gbar(bar, tgt); ++tgt;
  STAGE(u_g, u_lds);
  __syncthreads();
  const f32x4* ul4 = (const f32x4*)u_lds;
  const f32x4* vl4 = (const f32x4*)v_lds;

  for (int it = 0; it < 30; ++it){
    // v-update: v = b / (K^T u)
    {
      float s0 = 0.f, s1 = 0.f;
#pragma unroll
      for (int k = 0; k < 8; ++k){
        int idx = l + k * 64;
        if (idx < 500){
          f32x4 x = ul4[idx];
          s0 += kT0[k][0]*x[0] + kT0[k][1]*x[1] + kT0[k][2]*x[2] + kT0[k][3]*x[3];
          s1 += kT1[k][0]*x[0] + kT1[k][1]*x[1] + kT1[k][2]*x[2] + kT1[k][3]*x[3];
        }
      }
      s0 = wredSum(s0); s1 = wredSum(s1);
      if (l == 0){
        __hip_atomic_store(&v_g[r0], (b0 > 0.f) ? b0 / (s0 + 1e-8f) : 0.f,
                           __ATOMIC_RELAXED, __HIP_MEMORY_SCOPE_AGENT);
        __hip_atomic_store(&v_g[r1], (b1 > 0.f) ? b1 / (s1 + 1e-8f) : 0.f,
                           __ATOMIC_RELAXED, __HIP_MEMORY_SCOPE_AGENT);
      }
    }
    gbar(bar, tgt); ++tgt;
    STAGE(v_g, v_lds);
    __syncthreads();
    if (it < 29){
      // u-update: u = a / (K v)
      {
        float s0 = 0.f, s1 = 0.f;
#pragma unroll
        for (int k = 0; k < 8; ++k){
          int idx = l + k * 64;
          if (idx < 500){
            f32x4 x = vl4[idx];
            s0 += kA0[k][0]*x[0] + kA0[k][1]*x[1] + kA0[k][2]*x[2] + kA0[k][3]*x[3];
            s1 += kA1[k][0]*x[0] + kA1[k][1]*x[1] + kA1[k][2]*x[2] + kA1[k][3]*x[3];
          }
        }
        s0 = wredSum(s0); s1 = wredSum(s1);
        if (l == 0){
          __hip_atomic_store(&u_g[r0], (a0 > 0.f) ? a0 / (s0 + 1e-8f) : 0.f,
                             __ATOMIC_RELAXED, __HIP_MEMORY_SCOPE_AGENT);
          __hip_atomic_store(&u_g[r1], (a1 > 0.f) ? a1 / (s1 + 1e-8f) : 0.f,
                             __ATOMIC_RELAXED, __HIP_MEMORY_SCOPE_AGENT);
        }
      }
      gbar(bar, tgt); ++tgt;
      STAGE(u_g, u_lds);
      __syncthreads();
    }
  }
  // ---- row outputs: row_t + top-3 (butterfly keeps result in ALL lanes) ----
  float rf0, rf1;
  float rA0 = -1.f, rA1 = -1.f, rA2 = -1.f; int iA0 = 1<<30, iA1 = 1<<30, iA2 = 1<<30;
  float rB0 = -1.f, rB1 = -1.f, rB2 = -1.f; int iB0 = 1<<30, iB1 = 1<<30, iB2 = 1<<30;
  {
    float s0 = 0.f, s1 = 0.f;
#pragma unroll
    for (int k = 0; k < 8; ++k){
      int idx = l + k * 64;
      if (idx < 500){
        f32x4 x = vl4[idx];
        s0 += kA0[k][0]*x[0] + kA0[k][1]*x[1] + kA0[k][2]*x[2] + kA0[k][3]*x[3];
        s1 += kA1[k][0]*x[0] + kA1[k][1]*x[1] + kA1[k][2]*x[2] + kA1[k][3]*x[3];
      }
    }
    s0 = wredSum(s0); s1 = wredSum(s1);
    float uu0 = u_lds[r0], uu1 = u_lds[r1];
    rf0 = uu0 * (1.f / fmaxf(uu0 * s0, 1e-12f));
    rf1 = uu1 * (1.f / fmaxf(uu1 * s1, 1e-12f));
    f32x4* d0 = (f32x4*)(o0 + (size_t)r0 * CN);
    f32x4* d1 = (f32x4*)(o0 + (size_t)r1 * CN);
#pragma unroll
    for (int k = 0; k < 8; ++k){
      int idx = l + k * 64;
      if (idx < 500){
        f32x4 x = vl4[idx];
        f32x4 w0, w1;
#pragma unroll
        for (int q = 0; q < 4; ++q){
          w0[q] = rf0 * kA0[k][q] * x[q];
          w1[q] = rf1 * kA1[k][q] * x[q];
        }
        d0[idx] = w0; d1[idx] = w1;
#pragma unroll
        for (int q = 0; q < 4; ++q){
          int j = idx * 4 + q;
          INS3(rA0, rA1, rA2, iA0, iA1, iA2, w0[q], j);
          INS3(rB0, rB1, rB2, iB0, iB1, iB2, w1[q], j);
        }
      }
    }
#pragma unroll
    for (int o = 32; o >= 1; o >>= 1){
      float q0 = __shfl_xor(rA0, o, 64), q1 = __shfl_xor(rA1, o, 64), q2 = __shfl_xor(rA2, o, 64);
      int p0 = __shfl_xor(iA0, o, 64), p1 = __shfl_xor(iA1, o, 64), p2 = __shfl_xor(iA2, o, 64);
      float y0 = __shfl_xor(rB0, o, 64), y1 = __shfl_xor(rB1, o, 64), y2 = __shfl_xor(rB2, o, 64);
      int z0 = __shfl_xor(iB0, o, 64), z1 = __shfl_xor(iB1, o, 64), z2 = __shfl_xor(iB2, o, 64);
      INS3(rA0, rA1, rA2, iA0, iA1, iA2, q0, p0);
      INS3(rA0, rA1, rA2, iA0, iA1, iA2, q1, p1);
      INS3(rA0, rA1, rA2, iA0, iA1, iA2, q2, p2);
      INS3(rB0, rB1, rB2, iB0, iB1, iB2, y0, z0);
      INS3(rB0, rB1, rB2, iB0, iB1, iB2, y1, z1);
      INS3(rB0, rB1, rB2, iB0, iB1, iB2, y2, z2);
    }
  }
  // ---- col outputs: col_t + top-3 ----
  float cf0, cf1;
  float cA0 = -1.f, cA1 = -1.f, cA2 = -1.f; int jA0 = 1<<30, jA1 = 1<<30, jA2 = 1<<30;
  float cB0 = -1.f, cB1 = -1.f, cB2 = -1.f; int jB0 = 1<<30, jB1 = 1<<30, jB2 = 1<<30;
  {
    float s0 = 0.f, s1 = 0.f;
#pragma unroll
    for (int k = 0; k < 8; ++k){
      int idx = l + k * 64;
      if (idx < 500){
        f32x4 x = ul4[idx];
        s0 += kT0[k][0]*x[0] + kT0[k][1]*x[1] + kT0[k][2]*x[2] + kT0[k][3]*x[3];
        s1 += kT1[k][0]*x[0] + kT1[k][1]*x[1] + kT1[k][2]*x[2] + kT1[k][3]*x[3];
      }
    }
    s0 = wredSum(s0); s1 = wredSum(s1);
    float vv0 = v_lds[r0], vv1 = v_lds[r1];
    cf0 = vv0 * (1.f / fmaxf(vv0 * s0, 1e-12f));
    cf1 = vv1 * (1.f / fmaxf(vv1 * s1, 1e-12f));
    f32x4* d0 = (f32x4*)(o1 + (size_t)r0 * CN);
    f32x4* d1 = (f32x4*)(o1 + (size_t)r1 * CN);
#pragma unroll
    for (int k = 0; k < 8; ++k){
      int idx = l + k * 64;
      if (idx < 500){
        f32x4 x = ul4[idx];
        f32x4 w0, w1;
#pragma unroll
        for (int q = 0; q < 4; ++q){
          w0[q] = cf0 * kT0[k][q] * x[q];
          w1[q] = cf1 * kT1[k][q] * x[q];
        }
        d0[idx] = w0; d1[idx] = w1;
#pragma unroll
        for (int q = 0; q < 4; ++q){
          int j = idx * 4 + q;
          INS3(cA0, cA1, cA2, jA0, jA1, jA2, w0[q], j);
          INS3(cB0, cB1, cB2, jB0, jB1, jB2, w1[q], j);
        }
      }
    }
#pragma unroll
    for (int o = 32; o >= 1; o >>= 1){
      float q0 = __shfl_xor(cA0, o, 64), q1 = __shfl_xor(cA1, o, 64), q2 = __shfl_xor(cA2, o, 64);
      int p0 = __shfl_xor(jA0, o, 64), p1 = __shfl_xor(jA1, o, 64), p2 = __shfl_xor(jA2, o, 64);
      float y0 = __shfl_xor(cB0, o, 64), y1 = __shfl_xor(cB1, o, 64), y2 = __shfl_xor(cB2, o, 64);
      int z0 = __shfl_xor(jB0, o, 64), z1 = __shfl_xor(jB1, o, 64), z2 = __shfl_xor(jB2, o, 64);
      INS3(cA0, cA1, cA2, jA0, jA1, jA2, q0, p0);
      INS3(cA0, cA1, cA2, jA0, jA1, jA2, q1, p1);
      INS3(cA0, cA1, cA2, jA0, jA1, jA2, q2, p2);
      INS3(cB0, cB1, cB2, jB0, jB1, jB2, y0, z0);
      INS3(cB0, cB1, cB2, jB0, jB1, jB2, y1, z1);
      INS3(cB0, cB1, cB2, jB0, jB1, jB2, y2, z2);
    }
  }
  // publish col argmax for the cross-block mutual check
  if (l == 0){
    __hip_atomic_store(&cass[r0], jA0, __ATOMIC_RELAXED, __HIP_MEMORY_SCOPE_AGENT);
    __hip_atomic_store(&cass[r1], jB0, __ATOMIC_RELAXED, __HIP_MEMORY_SCOPE_AGENT);
  }
  gbar(bar, tgt); ++tgt;
  // ---- fused k_post: flags + fill o2..o5 for rows r0, r1 ----
  bool av0 = a0 > 0.f, av1 = a1 > 0.f;
  bool aiA = b0 > 0.f, aiB = b1 > 0.f;
  bool hi0 = av0 && (rA0 >= 0.55f), hi1 = av1 && (rB0 >= 0.55f);
  int caA = __hip_atomic_load(&cass[iA0 < CN ? iA0 : 0], __ATOMIC_RELAXED, __HIP_MEMORY_SCOPE_AGENT);
  int caB = __hip_atomic_load(&cass[iB0 < CN ? iB0 : 0], __ATOMIC_RELAXED, __HIP_MEMORY_SCOPE_AGENT);
  bool cm0 = hi0 && (caA == r0), cm1 = hi1 && (caB == r1);
  bool sp0 = hi0 && !cm0, sp1 = hi1 && !cm1;
  bool rr0 = av0 && (rA0 >= 0.25f) && (rA0 < 0.55f);
  bool rr1 = av1 && (rB0 >= 0.25f) && (rB0 < 0.55f);
  bool rc0 = aiA && (cA0 >= 0.25f) && (cA0 < 0.55f);
  bool rc1 = aiB && (cB0 >= 0.25f) && (cB0 < 0.55f);
  {
    f32x4* p2a = (f32x4*)(o2 + (size_t)r0 * CN);
    f32x4* p2b = (f32x4*)(o2 + (size_t)r1 * CN);
    f32x4* p3a = (f32x4*)(o3 + (size_t)r0 * CN);
    f32x4* p3b = (f32x4*)(o3 + (size_t)r1 * CN);
    f32x4* p4a = (f32x4*)(o4 + (size_t)r0 * CN);
    f32x4* p4b = (f32x4*)(o4 + (size_t)r1 * CN);
    f32x4* p5a = (f32x4*)(o5 + (size_t)r0 * CN);
    f32x4* p5b = (f32x4*)(o5 + (size_t)r1 * CN);
#pragma unroll
    for (int k = 0; k < 8; ++k){
      int idx = l + k * 64;
      if (idx < 500){
        f32x4 xv = vl4[idx], xu = ul4[idx];
        f32x4 e2a, e2b, e3a, e3b, e4a, e4b, e5a, e5b;
#pragma unroll
        for (int q = 0; q < 4; ++q){
          int j = idx * 4 + q;
          float w0 = rf0 * kA0[k][q] * xv[q];
          float w1 = rf1 * kA1[k][q] * xv[q];
          float c0 = cf0 * kT0[k][q] * xu[q];
          float c1 = cf1 * kT1[k][q] * xu[q];
          e2a[q] = (cm0 && j == iA0) ? rA0 : 0.f;
          e2b[q] = (cm1 && j == iB0) ? rB0 : 0.f;
          e3a[q] = sp0 ? w0 : 0.f;
          e3b[q] = sp1 ? w1 : 0.f;
          e4a[q] = (rr0 && (j == iA0 || j == iA1 || j == iA2)) ? w0 : 0.f;
          e4b[q] = (rr1 && (j == iB0 || j == iB1 || j == iB2)) ? w1 : 0.f;
          e5a[q] = (rc0 && (j == jA0 || j == jA1 || j == jA2)) ? c0 : 0.f;
          e5b[q] = (rc1 && (j == jB0 || j == jB1 || j == jB2)) ? c1 : 0.f;
        }
        p2a[idx] = e2a; p2b[idx] = e2b;
        p3a[idx] = e3a; p3b[idx] = e3b;
        p4a[idx] = e4a; p4b[idx] = e4b;
        p5a[idx] = e5a; p5b[idx] = e5b;
      }
    }
  }
}

extern "C" void kernel_launch(void* const* d_in, const int* in_sizes, int n_in,
                              void* d_out, int out_size, void* d_ws, size_t ws_size,
                              hipStream_t stream){
  (void)in_sizes; (void)n_in; (void)out_size; (void)ws_size;
  const float* visl = (const float*)d_in[0];
  const float* irl  = (const float*)d_in[1];
  const float* vm   = (const float*)d_in[2];
  const float* im   = (const float*)d_in[3];
  const int* rgb    = (const int*)d_in[4];
  const int* iri    = (const int*)d_in[5];
  float* out = (float*)d_out;
  float* o0 = out;                 // Km  -> row_t (in place)
  float* o1 = out + 4000000;       // imb(bf16) -> KTm -> col_t (in place)
  float* o2 = out + 8000000;       // proto_v -> common_rm
  float* o3 = out + 12000000;      // proto_i -> specific_rm
  float* o4 = out + 16000000;      // E -> remain_rm
  float* o5 = out + 20000000;      // vmb(bf16) -> remain_col_rm
  char* sm = (char*)d_ws;
  float* ev   = (float*)(sm + 0);
  float* ei   = (float*)(sm + 8000);
  float* rv   = (float*)(sm + 16000);
  float* ri   = (float*)(sm + 24000);
  float* uvec = (float*)(sm + 32000);
  float* vvec = (float*)(sm + 40000);
  int* bar    = (int*)(sm + 48000);   // [0]=root, [32]=gen, [64+g*32]=groups
  int* cass = (int*)(sm + 88000);
  int* cv   = (int*)(sm + 96000);
  int* ci   = (int*)(sm + 104000);
  int* ov   = (int*)(sm + 112000);
  int* oi   = (int*)(sm + 120000);
  int* curv = (int*)(sm + 128000);
  int* curi = (int*)(sm + 136000);
  int* ordv = (int*)(sm + 176000);
  int* ordi = (int*)(sm + 256000);
  unsigned short* vmb = (unsigned short*)o5;   // dead until k_sink fill
  unsigned short* imb = (unsigned short*)o1;   // dead until k_tr (after gemm2)

  k_zero<<<47, 256, 0, stream>>>(cv, 12000, bar);  // cv..curi contiguous + barrier vars
  k_hist<<<157, 256, 0, stream>>>(rgb, iri, cv, ci);
  k_scan<<<1, 1024, 0, stream>>>(cv, ci, ov, oi);
  k_scatter<<<157, 256, 0, stream>>>(rgb, iri, ov, oi, curv, curi, ordv, ordi);
  k_class<<<2 * CN + 1000, 256, 0, stream>>>(visl, irl, cv, ci, ov, oi, ordv, ordi,
                                             o2, o3, ev, ei, vm, im, vmb, imb, rv, ri);
  k_prep<<<dim3(32, 32), 256, 0, stream>>>(o2, o3, ev, ei, cv, ci, o4);
  k_gemm2<<<dim3(16, 16), 256, 0, stream>>>(vmb, imb, rv, ri, o4, o0);
  k_tr<<<dim3(32, 32), 256, 0, stream>>>(o0, o1);
  k_sink<<<NBLK, 512, 0, stream>>>(o0, o1, cv, ci, uvec, vvec, o0, o1,
                                   cass, bar, o2, o3, o4, o5);
}

// Round 14
// 422.619 us; speedup vs baseline: 1.3834x; 1.3834x over previous
//
#include <hip/hip_runtime.h>

#define CN 2000
#define DF 2048
#define NS 20000
#define NBLK 125
#define NGRP 25
#define GRPSZ 5

typedef __attribute__((ext_vector_type(4))) float          f32x4;
typedef __attribute__((ext_vector_type(4))) int            i32x4;
typedef __attribute__((ext_vector_type(4))) unsigned short u16x4;

__device__ __forceinline__ float wredSum(float v){
#pragma unroll
  for (int o = 32; o >= 1; o >>= 1) v += __shfl_xor(v, o, 64);
  return v;
}
__device__ __forceinline__ float wredMax(float v){
#pragma unroll
  for (int o = 32; o >= 1; o >>= 1) v = fmaxf(v, __shfl_xor(v, o, 64));
  return v;
}
__device__ __forceinline__ unsigned short bfbits(float x){
  union { float f; unsigned u; } c; c.f = x;
  return (unsigned short)((c.u + 0x7fffu + ((c.u >> 16) & 1u)) >> 16);
}
__device__ __forceinline__ void gload16(const void* g, void* lds){
  __builtin_amdgcn_global_load_lds((const __attribute__((address_space(1))) unsigned int*)g,
      (__attribute__((address_space(3))) unsigned int*)lds, 16, 0, 0);
}

// Fence-free monotonic hierarchical grid barrier (agent-scope atomics only).
// bar[0]=root, bar[32]=generation, bar[64+g*32]=group counters. The leading
// s_waitcnt vmcnt(0) drains each thread's own stores before arrival.
__device__ __forceinline__ void gbar(int* bar, int target){
  asm volatile("s_waitcnt vmcnt(0)" ::: "memory");
  __syncthreads();
  if (threadIdx.x == 0){
    int g = blockIdx.x / GRPSZ;
    int prev = __hip_atomic_fetch_add(&bar[64 + g * 32], 1,
                  __ATOMIC_RELAXED, __HIP_MEMORY_SCOPE_AGENT);
    if (prev == target * GRPSZ - 1){
      int rp = __hip_atomic_fetch_add(&bar[0], 1,
                  __ATOMIC_RELAXED, __HIP_MEMORY_SCOPE_AGENT);
      if (rp == target * NGRP - 1){
        __hip_atomic_store(&bar[32], target, __ATOMIC_RELAXED, __HIP_MEMORY_SCOPE_AGENT);
      }
    }
    while (__hip_atomic_load(&bar[32], __ATOMIC_RELAXED, __HIP_MEMORY_SCOPE_AGENT) < target){
      __builtin_amdgcn_s_sleep(1);
    }
  }
  __syncthreads();
}

__global__ void k_zero(int* p, int n, int* bar){
  int i = blockIdx.x * 256 + threadIdx.x;
  if (i < n) p[i] = 0;
  if (i < 1024) bar[i] = 0;
}

__global__ void k_hist(const int* __restrict__ rgb, const int* __restrict__ iri,
                       int* cv, int* ci){
  int i = blockIdx.x * 256 + threadIdx.x;
  if (i < NS) atomicAdd(&cv[rgb[i]], 1);
  else if (i < 2 * NS) atomicAdd(&ci[iri[i - NS]], 1);
}

__global__ __launch_bounds__(1024) void k_scan(const int* __restrict__ cv, const int* __restrict__ ci,
                                               int* ov, int* oi){
  __shared__ int s[2048];
  int t = threadIdx.x;
  for (int pass = 0; pass < 2; ++pass){
    const int* c = pass ? ci : cv;
    int* o = pass ? oi : ov;
    s[t] = (t < CN) ? c[t] : 0;
    s[t + 1024] = (t + 1024 < CN) ? c[t + 1024] : 0;
    __syncthreads();
    for (int off = 1; off < 2048; off <<= 1){
      int a = (t >= off) ? s[t - off] : 0;
      int b = (t + 1024 >= off) ? s[t + 1024 - off] : 0;
      __syncthreads();
      s[t] += a; s[t + 1024] += b;
      __syncthreads();
    }
    if (t < CN) o[t] = s[t] - c[t];
    if (t + 1024 < CN) o[t + 1024] = s[t + 1024] - c[t + 1024];
    __syncthreads();
  }
}

__global__ void k_scatter(const int* __restrict__ rgb, const int* __restrict__ iri,
                          const int* __restrict__ ov, const int* __restrict__ oi,
                          int* curv, int* curi, int* ordv, int* ordi){
  int i = blockIdx.x * 256 + threadIdx.x;
  if (i < NS){
    int l = rgb[i];
    int p = atomicAdd(&curv[l], 1);
    ordv[ov[l] + p] = i;
  } else if (i < 2 * NS){
    int k = i - NS;
    int l = iri[k];
    int p = atomicAdd(&curi[l], 1);
    ordi[oi[l] + p] = k;
  }
}

// Blocks [0, 2*CN): one block per (modality,class) — softmax+proto+entropy.
// Blocks [2*CN, 2*CN+1000): f32->bf16 conversion + row-norm.
// vmb/imb live in o5/o1 (dead until k_post / k_tr).
__global__ __launch_bounds__(256) void k_class(const float* __restrict__ visl, const float* __restrict__ irl,
    const int* __restrict__ cv, const int* __restrict__ ci,
    const int* __restrict__ ov, const int* __restrict__ oi,
    const int* __restrict__ ordv, const int* __restrict__ ordi,
    float* __restrict__ pv, float* __restrict__ pi_,
    float* __restrict__ ev, float* __restrict__ ei,
    const float* __restrict__ vm, const float* __restrict__ im,
    unsigned short* __restrict__ vmb, unsigned short* __restrict__ imb,
    float* __restrict__ rv, float* __restrict__ ri){
  if (blockIdx.x >= 2 * CN){
    int g = (blockIdx.x - 2 * CN) * 256 + threadIdx.x;
    int wid = g >> 6, l = g & 63;
    if (wid >= 2 * CN) return;
    const float* src = (wid < CN) ? vm : im;
    unsigned short* dst = (wid < CN) ? vmb : imb;
    int r = (wid < CN) ? wid : wid - CN;
    const f32x4* row = (const f32x4*)(src + (size_t)r * DF);
    float s = 0.f;
#pragma unroll
    for (int k = 0; k < 8; ++k){
      int idx = l + k * 64;
      f32x4 vv = row[idx];
      s += vv[0]*vv[0] + vv[1]*vv[1] + vv[2]*vv[2] + vv[3]*vv[3];
      u16x4 o;
      o[0] = bfbits(vv[0]); o[1] = bfbits(vv[1]); o[2] = bfbits(vv[2]); o[3] = bfbits(vv[3]);
      *(u16x4*)(dst + (size_t)r * DF + idx * 4) = o;
    }
    s = wredSum(s);
    if (l == 0) ((wid < CN) ? rv : ri)[r] = 1.f / fmaxf(sqrtf(s), 1e-12f);
    return;
  }
  __shared__ __attribute__((aligned(16))) float acc4[4][2048];
  __shared__ int mem[128];
  __shared__ float red[4];
  int t = threadIdx.x, w = t >> 6, l = t & 63;
  bool ir = (blockIdx.x >= CN);
  int c = ir ? blockIdx.x - CN : blockIdx.x;
  const float* logits = ir ? irl : visl;
  int n = (ir ? ci : cv)[c];
  int base = (ir ? oi : ov)[c];
  const int* ord = ir ? ordi : ordv;
  float* proto = ir ? pi_ : pv;
  float* ent = ir ? ei : ev;
  bool useL = (n <= 128);
  for (int m = t; m < n && m < 128; m += 256) mem[m] = ord[base + m];
  for (int j = t; j < 2048; j += 256){
    acc4[0][j] = 0.f; acc4[1][j] = 0.f; acc4[2][j] = 0.f; acc4[3][j] = 0.f;
  }
  __syncthreads();
  if (t == 0 && useL){  // deterministic member order across replays
    for (int a = 1; a < n; ++a){
      int key = mem[a]; int b = a - 1;
      while (b >= 0 && mem[b] > key){ mem[b + 1] = mem[b]; --b; }
      mem[b + 1] = key;
    }
  }
  __syncthreads();
  for (int m = w; m < n; m += 4){
    int sidx = useL ? mem[m] : ord[base + m];
    const f32x4* row = (const f32x4*)(logits + (size_t)sidx * CN);
    f32x4 x[8]; float mx = -3.0e38f;
#pragma unroll
    for (int k = 0; k < 8; ++k){
      int idx = l + k * 64;
      f32x4 vv = {-3.0e38f, -3.0e38f, -3.0e38f, -3.0e38f};
      if (idx < 500) vv = row[idx];
      x[k] = vv;
      mx = fmaxf(mx, fmaxf(fmaxf(vv[0], vv[1]), fmaxf(vv[2], vv[3])));
    }
    mx = wredMax(mx);
    float sm = 0.f;
#pragma unroll
    for (int k = 0; k < 8; ++k){
      int idx = l + k * 64;
      if (idx < 500){
        f32x4 e;
        e[0] = expf(x[k][0] - mx); e[1] = expf(x[k][1] - mx);
        e[2] = expf(x[k][2] - mx); e[3] = expf(x[k][3] - mx);
        x[k] = e;
        sm += e[0] + e[1] + e[2] + e[3];
      }
    }
    sm = wredSum(sm);
    float inv = 1.f / sm;
#pragma unroll
    for (int k = 0; k < 8; ++k){
      int idx = l + k * 64;
      if (idx < 500){
        f32x4* a = (f32x4*)&acc4[w][idx * 4];
        f32x4 cur = *a;
        cur[0] += x[k][0] * inv; cur[1] += x[k][1] * inv;
        cur[2] += x[k][2] * inv; cur[3] += x[k][3] * inv;
        *a = cur;
      }
    }
  }
  __syncthreads();
  float invc = 1.f / fmaxf((float)n, 1.f);
  float el = 0.f;
  for (int j = t; j < CN; j += 256){
    float p = (acc4[0][j] + acc4[1][j] + acc4[2][j] + acc4[3][j]) * invc;
    proto[(size_t)c * CN + j] = p;
    p = fmaxf(p, 1e-12f);
    el -= p * logf(p);
  }
  el = wredSum(el);
  if (l == 0) red[w] = el;
  __syncthreads();
  if (t == 0) ent[c] = red[0] + red[1] + red[2] + red[3];
}

// E[i][j] = active ? exp(-(0.45*(1-pred) + 0.15*(1-conf))/0.07) : 0
__global__ __launch_bounds__(256) void k_prep(const float* __restrict__ pv, const float* __restrict__ pi_,
    const float* __restrict__ ev, const float* __restrict__ ei,
    const int* __restrict__ cv, const int* __restrict__ ci, float* __restrict__ E){
  __shared__ float s[64][65];
  int t = threadIdx.x;
  int i0 = blockIdx.y * 64, j0 = blockIdx.x * 64;
#pragma unroll
  for (int rr = 0; rr < 4; ++rr){
    int jl = (t >> 4) + rr * 16;
    int ch = t & 15;
    int gj = j0 + jl;
    int gib = i0 + ch * 4;
    f32x4 vv = {0.f, 0.f, 0.f, 0.f};
    if (gj < CN){
      if (gib + 3 < CN) vv = *(const f32x4*)(pi_ + (size_t)gj * CN + gib);
      else {
        for (int q = 0; q < 4; ++q) if (gib + q < CN) vv[q] = pi_[(size_t)gj * CN + gib + q];
      }
    }
    s[ch*4+0][jl] = vv[0]; s[ch*4+1][jl] = vv[1]; s[ch*4+2][jl] = vv[2]; s[ch*4+3][jl] = vv[3];
  }
  __syncthreads();
#pragma unroll
  for (int rr = 0; rr < 4; ++rr){
    int il = (t >> 4) + rr * 16;
    int ch = t & 15;
    int gi = i0 + il;
    int gjb = j0 + ch * 4;
    if (gi >= CN) continue;
    f32x4 pvv = {0.f, 0.f, 0.f, 0.f};
    bool full = (gjb + 3 < CN);
    if (full) pvv = *(const f32x4*)(pv + (size_t)gi * CN + gjb);
    else { for (int q = 0; q < 4; ++q) if (gjb + q < CN) pvv[q] = pv[(size_t)gi * CN + gjb + q]; }
    float evi = ev[gi];
    bool avi = cv[gi] > 0;
    f32x4 o;
#pragma unroll
    for (int q = 0; q < 4; ++q){
      int gj = gjb + q;
      if (gj >= CN){ o[q] = 0.f; continue; }
      float pred = 0.5f * (pvv[q] + s[il][ch*4+q]);
      float conf = fminf(fmaxf(1.f - (evi + ei[gj]) / 15.201804919084164f, 0.f), 1.f);
      float base = 0.45f * (1.f - pred) + 0.15f * (1.f - conf);
      bool act = avi && (ci[gj] > 0);
      o[q] = act ? expf(-base / 0.07f) : 0.f;
    }
    if (full) *(f32x4*)(E + (size_t)gi * CN + gjb) = o;
    else { for (int q = 0; q < 4; ++q) if (gjb + q < CN) E[(size_t)gi * CN + gjb + q] = o[q]; }
  }
}

// bf16 MFMA GEMM, 128x128 tile, BK=64, global_load_lds staging with XOR
// swizzle + XCD-aware block swizzle (256 wgs, bijective).
__global__ __launch_bounds__(256) void k_gemm2(const unsigned short* __restrict__ Ag,
    const unsigned short* __restrict__ Bg, const float* __restrict__ rv,
    const float* __restrict__ ri, const float* __restrict__ E, float* __restrict__ Km){
  __shared__ __attribute__((aligned(16))) unsigned short As[128 * 64];
  __shared__ __attribute__((aligned(16))) unsigned short Bs[128 * 64];
  int t = threadIdx.x, w = t >> 6, l = t & 63;
  int bid = blockIdx.y * 16 + blockIdx.x;
  int swz = (bid & 7) * 32 + (bid >> 3);
  int i0 = (swz >> 4) * 128, j0 = (swz & 15) * 128;
  int wm = w >> 1, wn = w & 1;
  int srow8 = l >> 3, sch = l & 7;
  int lr = l & 15, hk = l >> 4;
  f32x4 z = {0.f, 0.f, 0.f, 0.f};
  f32x4 acc[4][4];
#pragma unroll
  for (int a = 0; a < 4; ++a)
#pragma unroll
    for (int b = 0; b < 4; ++b) acc[a][b] = z;

  for (int kt = 0; kt < DF / 64; ++kt){
    int k0 = kt * 64;
#pragma unroll
    for (int c2 = 0; c2 < 4; ++c2){
      int rbase = c2 * 32 + w * 8;
      int row = rbase + srow8;
      int lch = sch ^ (srow8 & 7);
      int gi = i0 + row; if (gi > CN - 1) gi = CN - 1;
      int gj = j0 + row; if (gj > CN - 1) gj = CN - 1;
      gload16(Ag + (size_t)gi * DF + k0 + lch * 8, &As[rbase * 64]);
      gload16(Bg + (size_t)gj * DF + k0 + lch * 8, &Bs[rbase * 64]);
    }
    __syncthreads();
#pragma unroll
    for (int s2 = 0; s2 < 2; ++s2){
      i32x4 af[4], bf[4];
#pragma unroll
      for (int f2 = 0; f2 < 4; ++f2){
        int ar = wm * 64 + f2 * 16 + lr;
        int ac = (s2 * 4 + hk) ^ (ar & 7);
        af[f2] = *(const i32x4*)&As[ar * 64 + ac * 8];
        int br = wn * 64 + f2 * 16 + lr;
        int bc = (s2 * 4 + hk) ^ (br & 7);
        bf[f2] = *(const i32x4*)&Bs[br * 64 + bc * 8];
      }
#pragma unroll
      for (int a = 0; a < 4; ++a)
#pragma unroll
        for (int b = 0; b < 4; ++b)
          asm volatile("v_mfma_f32_16x16x32_bf16 %0, %1, %2, %0"
                       : "+v"(acc[a][b]) : "v"(af[a]), "v"(bf[b]));
    }
    __syncthreads();
  }
#pragma unroll
  for (int a = 0; a < 4; ++a){
    int ib = i0 + wm * 64 + a * 16 + hk * 4;
#pragma unroll
    for (int b = 0; b < 4; ++b){
      int j = j0 + wn * 64 + b * 16 + lr;
      if (j < CN){
        float rij = ri[j];
#pragma unroll
        for (int q = 0; q < 4; ++q){
          int i = ib + q;
          if (i < CN){
            float dot = acc[a][b][q] * rv[i] * rij;
            float feat = fminf(fmaxf((dot + 1.f) * 0.5f, 0.f), 1.f);
            float kv = E[(size_t)i * CN + j] * expf(-0.4f * (1.f - feat) / 0.07f);
            Km[(size_t)i * CN + j] = kv;
          }
        }
      }
    }
  }
}

// 64x64 LDS transpose: KT = Km^T (overwrites imb — safe, gemm2 already done)
__global__ __launch_bounds__(256) void k_tr(const float* __restrict__ Km, float* __restrict__ KT){
  __shared__ float s[64][65];
  int t = threadIdx.x;
  int i0 = blockIdx.y * 64, j0 = blockIdx.x * 64;
#pragma unroll
  for (int rr = 0; rr < 4; ++rr){
    int il = (t >> 4) + rr * 16;
    int ch = t & 15;
    int gi = i0 + il, gjb = j0 + ch * 4;
    f32x4 vv = {0.f, 0.f, 0.f, 0.f};
    if (gi < CN){
      if (gjb + 3 < CN) vv = *(const f32x4*)(Km + (size_t)gi * CN + gjb);
      else { for (int q = 0; q < 4; ++q) if (gjb + q < CN) vv[q] = Km[(size_t)gi * CN + gjb + q]; }
    }
    s[ch*4+0][il] = vv[0]; s[ch*4+1][il] = vv[1]; s[ch*4+2][il] = vv[2]; s[ch*4+3][il] = vv[3];
  }
  __syncthreads();
#pragma unroll
  for (int rr = 0; rr < 4; ++rr){
    int jl = (t >> 4) + rr * 16;
    int ch = t & 15;
    int gj = j0 + jl, gib = i0 + ch * 4;
    if (gj >= CN) continue;
    f32x4 o;
    o[0] = s[jl][ch*4+0]; o[1] = s[jl][ch*4+1]; o[2] = s[jl][ch*4+2]; o[3] = s[jl][ch*4+3];
    if (gib + 3 < CN) *(f32x4*)(KT + (size_t)gj * CN + gib) = o;
    else { for (int q = 0; q < 4; ++q) if (gib + q < CN) KT[(size_t)gj * CN + gib + q] = o[q]; }
  }
}

#define STAGE(G, L) do { \
  float tmp_[4]; \
  _Pragma("unroll") \
  for (int k_ = 0; k_ < 4; ++k_){ \
    int idx_ = t + k_ * 512; \
    tmp_[k_] = (idx_ < CN) ? __hip_atomic_load(&(G)[idx_], __ATOMIC_RELAXED, __HIP_MEMORY_SCOPE_AGENT) : 0.f; \
  } \
  _Pragma("unroll") \
  for (int k_ = 0; k_ < 4; ++k_){ int idx_ = t + k_ * 512; if (idx_ < CN) (L)[idx_] = tmp_[k_]; } \
} while(0)

// Persistent Sinkhorn: 125 blocks x 512 (16 rows/block, 2 rows/wave x 8 waves),
// fence-free barriers. Each wave holds 2 K-rows + 2 KT-rows in registers; u/v
// exchanged via agent-scope atomics, staged coalesced into LDS per block after
// each barrier. 60 barriers.
__global__ __launch_bounds__(512, 1) void k_sink(
    const float* __restrict__ Km, const float* __restrict__ KTm,
    const int* __restrict__ cv, const int* __restrict__ ci,
    float* __restrict__ u_g, float* __restrict__ v_g,
    float* __restrict__ o0, float* __restrict__ o1,
    float* __restrict__ rconf, float* __restrict__ cconf,
    int* __restrict__ rass, int* __restrict__ cass,
    int* bar){
  __shared__ __attribute__((aligned(16))) float u_lds[2048];
  __shared__ __attribute__((aligned(16))) float v_lds[2048];
  int b = blockIdx.x, t = threadIdx.x, w = t >> 6, l = t & 63;
  int r0 = b * 16 + w * 2, r1 = r0 + 1;
  f32x4 z4 = {0.f, 0.f, 0.f, 0.f};
  f32x4 kA0[8], kA1[8], kT0[8], kT1[8];
  {
    const f32x4* g0 = (const f32x4*)(Km + (size_t)r0 * CN);
    const f32x4* g1 = (const f32x4*)(Km + (size_t)r1 * CN);
    const f32x4* h0 = (const f32x4*)(KTm + (size_t)r0 * CN);
    const f32x4* h1 = (const f32x4*)(KTm + (size_t)r1 * CN);
#pragma unroll
    for (int k = 0; k < 8; ++k){
      int idx = l + k * 64;
      bool ok = idx < 500;
      kA0[k] = ok ? g0[idx] : z4;
      kA1[k] = ok ? g1[idx] : z4;
      kT0[k] = ok ? h0[idx] : z4;
      kT1[k] = ok ? h1[idx] : z4;
    }
  }
  float a0 = (float)cv[r0] / 20000.0f, a1 = (float)cv[r1] / 20000.0f;
  float b0 = (float)ci[r0] / 20000.0f, b1 = (float)ci[r1] / 20000.0f;

  // iteration 0 u-update: v === 1, so Kv = rowsum(K)
  {
    float s0 = 0.f, s1 = 0.f;
#pragma unroll
    for (int k = 0; k < 8; ++k){
      s0 += kA0[k][0] + kA0[k][1] + kA0[k][2] + kA0[k][3];
      s1 += kA1[k][0] + kA1[k][1] + kA1[k][2] + kA1[k][3];
    }
    s0 = wredSum(s0); s1 = wredSum(s1);
    if (l == 0){
      __hip_atomic_store(&u_g[r0], (a0 > 0.f) ? a0 / (s0 + 1e-8f) : 0.f,
                         __ATOMIC_RELAXED, __HIP_MEMORY_SCOPE_AGENT);
      __hip_atomic_store(&u_g[r1], (a1 > 0.f) ? a1 / (s1 + 1e-8f) : 0.f,
                         __ATOMIC_RELAXED, __HIP_MEMORY_SCOPE_AGENT);
    }
  }
  int tgt = 1;
  gbar(bar, tgt); ++tgt;
  STAGE(u_g, u_lds);
  __syncthreads();
  const f32x4* ul4 = (const f32x4*)u_lds;
  const f32x4* vl4 = (const f32x4*)v_lds;

  for (int it = 0; it < 30; ++it){
    // v-update: v = b / (K^T u)
    {
      float s0 = 0.f, s1 = 0.f;
#pragma unroll
      for (int k = 0; k < 8; ++k){
        int idx = l + k * 64;
        if (idx < 500){
          f32x4 x = ul4[idx];
          s0 += kT0[k][0]*x[0] + kT0[k][1]*x[1] + kT0[k][2]*x[2] + kT0[k][3]*x[3];
          s1 += kT1[k][0]*x[0] + kT1[k][1]*x[1] + kT1[k][2]*x[2] + kT1[k][3]*x[3];
        }
      }
      s0 = wredSum(s0); s1 = wredSum(s1);
      if (l == 0){
        __hip_atomic_store(&v_g[r0], (b0 > 0.f) ? b0 / (s0 + 1e-8f) : 0.f,
                           __ATOMIC_RELAXED, __HIP_MEMORY_SCOPE_AGENT);
        __hip_atomic_store(&v_g[r1], (b1 > 0.f) ? b1 / (s1 + 1e-8f) : 0.f,
                           __ATOMIC_RELAXED, __HIP_MEMORY_SCOPE_AGENT);
      }
    }
    gbar(bar, tgt); ++tgt;
    STAGE(v_g, v_lds);
    __syncthreads();
    if (it < 29){
      // u-update: u = a / (K v)
      {
        float s0 = 0.f, s1 = 0.f;
#pragma unroll
        for (int k = 0; k < 8; ++k){
          int idx = l + k * 64;
          if (idx < 500){
            f32x4 x = vl4[idx];
            s0 += kA0[k][0]*x[0] + kA0[k][1]*x[1] + kA0[k][2]*x[2] + kA0[k][3]*x[3];
            s1 += kA1[k][0]*x[0] + kA1[k][1]*x[1] + kA1[k][2]*x[2] + kA1[k][3]*x[3];
          }
        }
        s0 = wredSum(s0); s1 = wredSum(s1);
        if (l == 0){
          __hip_atomic_store(&u_g[r0], (a0 > 0.f) ? a0 / (s0 + 1e-8f) : 0.f,
                             __ATOMIC_RELAXED, __HIP_MEMORY_SCOPE_AGENT);
          __hip_atomic_store(&u_g[r1], (a1 > 0.f) ? a1 / (s1 + 1e-8f) : 0.f,
                             __ATOMIC_RELAXED, __HIP_MEMORY_SCOPE_AGENT);
        }
      }
      gbar(bar, tgt); ++tgt;
      STAGE(u_g, u_lds);
      __syncthreads();
    }
  }
  // row outputs: row_t = u_r*K[r][:]*v[:] / max(u_r*dot(K[r],v),1e-12)
  {
    float s0 = 0.f, s1 = 0.f;
#pragma unroll
    for (int k = 0; k < 8; ++k){
      int idx = l + k * 64;
      if (idx < 500){
        f32x4 x = vl4[idx];
        s0 += kA0[k][0]*x[0] + kA0[k][1]*x[1] + kA0[k][2]*x[2] + kA0[k][3]*x[3];
        s1 += kA1[k][0]*x[0] + kA1[k][1]*x[1] + kA1[k][2]*x[2] + kA1[k][3]*x[3];
      }
    }
    s0 = wredSum(s0); s1 = wredSum(s1);
    float uu0 = u_lds[r0], uu1 = u_lds[r1];
    float f0 = uu0 * (1.f / fmaxf(uu0 * s0, 1e-12f));
    float f1 = uu1 * (1.f / fmaxf(uu1 * s1, 1e-12f));
    float bm0 = -1e30f, bm1 = -1e30f; int bi0 = 1 << 30, bi1 = 1 << 30;
    f32x4* d0 = (f32x4*)(o0 + (size_t)r0 * CN);
    f32x4* d1 = (f32x4*)(o0 + (size_t)r1 * CN);
#pragma unroll
    for (int k = 0; k < 8; ++k){
      int idx = l + k * 64;
      if (idx < 500){
        f32x4 x = vl4[idx];
        f32x4 w0, w1;
#pragma unroll
        for (int q = 0; q < 4; ++q){
          w0[q] = f0 * kA0[k][q] * x[q];
          w1[q] = f1 * kA1[k][q] * x[q];
        }
        d0[idx] = w0; d1[idx] = w1;
#pragma unroll
        for (int q = 0; q < 4; ++q){
          int j = idx * 4 + q;
          if (w0[q] > bm0){ bm0 = w0[q]; bi0 = j; }
          if (w1[q] > bm1){ bm1 = w1[q]; bi1 = j; }
        }
      }
    }
#pragma unroll
    for (int o = 32; o >= 1; o >>= 1){
      float om = __shfl_xor(bm0, o, 64); int oi2 = __shfl_xor(bi0, o, 64);
      if (om > bm0 || (om == bm0 && oi2 < bi0)){ bm0 = om; bi0 = oi2; }
      float om1 = __shfl_xor(bm1, o, 64); int oi3 = __shfl_xor(bi1, o, 64);
      if (om1 > bm1 || (om1 == bm1 && oi3 < bi1)){ bm1 = om1; bi1 = oi3; }
    }
    if (l == 0){ rconf[r0] = bm0; rass[r0] = bi0; rconf[r1] = bm1; rass[r1] = bi1; }
  }
  // col outputs
  {
    float s0 = 0.f, s1 = 0.f;
#pragma unroll
    for (int k = 0; k < 8; ++k){
      int idx = l + k * 64;
      if (idx < 500){
        f32x4 x = ul4[idx];
        s0 += kT0[k][0]*x[0] + kT0[k][1]*x[1] + kT0[k][2]*x[2] + kT0[k][3]*x[3];
        s1 += kT1[k][0]*x[0] + kT1[k][1]*x[1] + kT1[k][2]*x[2] + kT1[k][3]*x[3];
      }
    }
    s0 = wredSum(s0); s1 = wredSum(s1);
    float vv0 = v_lds[r0], vv1 = v_lds[r1];
    float f0 = vv0 * (1.f / fmaxf(vv0 * s0, 1e-12f));
    float f1 = vv1 * (1.f / fmaxf(vv1 * s1, 1e-12f));
    float bm0 = -1e30f, bm1 = -1e30f; int bi0 = 1 << 30, bi1 = 1 << 30;
    f32x4* d0 = (f32x4*)(o1 + (size_t)r0 * CN);
    f32x4* d1 = (f32x4*)(o1 + (size_t)r1 * CN);
#pragma unroll
    for (int k = 0; k < 8; ++k){
      int idx = l + k * 64;
      if (idx < 500){
        f32x4 x = ul4[idx];
        f32x4 w0, w1;
#pragma unroll
        for (int q = 0; q < 4; ++q){
          w0[q] = f0 * kT0[k][q] * x[q];
          w1[q] = f1 * kT1[k][q] * x[q];
        }
        d0[idx] = w0; d1[idx] = w1;
#pragma unroll
        for (int q = 0; q < 4; ++q){
          int j = idx * 4 + q;
          if (w0[q] > bm0){ bm0 = w0[q]; bi0 = j; }
          if (w1[q] > bm1){ bm1 = w1[q]; bi1 = j; }
        }
      }
    }
#pragma unroll
    for (int o = 32; o >= 1; o >>= 1){
      float om = __shfl_xor(bm0, o, 64); int oi2 = __shfl_xor(bi0, o, 64);
      if (om > bm0 || (om == bm0 && oi2 < bi0)){ bm0 = om; bi0 = oi2; }
      float om1 = __shfl_xor(bm1, o, 64); int oi3 = __shfl_xor(bi1, o, 64);
      if (om1 > bm1 || (om1 == bm1 && oi3 < bi1)){ bm1 = om1; bi1 = oi3; }
    }
    if (l == 0){ cconf[r0] = bm0; cass[r0] = bi0; cconf[r1] = bm1; cass[r1] = bi1; }
  }
}

// Merged fill + topk: one block per row i. Zeros o2..o5 rows, writes common/
// specific, then scatters row-topk into o4 and col-topk into o5.
__global__ __launch_bounds__(256) void k_post(const float* __restrict__ rt, const float* __restrict__ ct,
    const int* __restrict__ cv, const int* __restrict__ ci,
    const float* __restrict__ rc, const float* __restrict__ cc,
    const int* __restrict__ ra, const int* __restrict__ ca,
    float* o2, float* o3, float* o4, float* o5){
  __shared__ float sv[256 * 3];
  __shared__ int si[256 * 3];
  int i = blockIdx.x, t = threadIdx.x;
  bool av = cv[i] > 0, ai = ci[i] > 0;
  float rcv = rc[i], ccv = cc[i];
  int aidx = ra[i];
  bool high = av && (rcv >= 0.55f);
  bool cm = high && (ca[aidx] == i);
  bool sp = high && !cm;
  bool remr = av && (rcv >= 0.25f) && (rcv < 0.55f);
  bool remc = ai && (ccv >= 0.25f) && (ccv < 0.55f);
  f32x4 z = {0.f, 0.f, 0.f, 0.f};
  f32x4* p2 = (f32x4*)(o2 + (size_t)i * CN);
  f32x4* p3 = (f32x4*)(o3 + (size_t)i * CN);
  f32x4* p4 = (f32x4*)(o4 + (size_t)i * CN);
  f32x4* p5 = (f32x4*)(o5 + (size_t)i * CN);
  const f32x4* rp = (const f32x4*)(rt + (size_t)i * CN);
  for (int c = t; c < 500; c += 256){
    p2[c] = z;
    p3[c] = sp ? rp[c] : z;
    p4[c] = z;
    p5[c] = z;
  }
  __syncthreads();
  if (t == 0 && cm) o2[(size_t)i * CN + aidx] = rcv;
  for (int pass = 0; pass < 2; ++pass){
    bool run = pass ? remc : remr;
    if (!run) continue;
    const float* M = pass ? ct : rt;
    float* o = pass ? o5 : o4;
    float v0 = -1.f, v1 = -1.f, v2 = -1.f;
    int i0 = 1 << 30, i1 = 1 << 30, i2 = 1 << 30;
    for (int k = 0; k < 8; ++k){
      int j = t + k * 256;
      if (j >= CN) break;
      float val = M[(size_t)i * CN + j];
      if (val > v0 || (val == v0 && j < i0)){ v2=v1; i2=i1; v1=v0; i1=i0; v0=val; i0=j; }
      else if (val > v1 || (val == v1 && j < i1)){ v2=v1; i2=i1; v1=val; i1=j; }
      else if (val > v2 || (val == v2 && j < i2)){ v2=val; i2=j; }
    }
    sv[t*3+0]=v0; sv[t*3+1]=v1; sv[t*3+2]=v2;
    si[t*3+0]=i0; si[t*3+1]=i1; si[t*3+2]=i2;
    __syncthreads();
    if (t == 0){
      float w0=-1.f, w1=-1.f, w2=-1.f; int j0=1<<30, j1=1<<30, j2=1<<30;
      for (int q = 0; q < 256 * 3; ++q){
        float val = sv[q]; int j = si[q];
        if (j >= CN) continue;
        if (val > w0 || (val == w0 && j < j0)){ w2=w1; j2=j1; w1=w0; j1=j0; w0=val; j0=j; }
        else if (val > w1 || (val == w1 && j < j1)){ w2=w1; j2=j1; w1=val; j1=j; }
        else if (val > w2 || (val == w2 && j < j2)){ w2=val; j2=j; }
      }
      o[(size_t)i * CN + j0] = w0;
      o[(size_t)i * CN + j1] = w1;
      o[(size_t)i * CN + j2] = w2;
    }
    __syncthreads();
  }
}

extern "C" void kernel_launch(void* const* d_in, const int* in_sizes, int n_in,
                              void* d_out, int out_size, void* d_ws, size_t ws_size,
                              hipStream_t stream){
  (void)in_sizes; (void)n_in; (void)out_size; (void)ws_size;
  const float* visl = (const float*)d_in[0];
  const float* irl  = (const float*)d_in[1];
  const float* vm   = (const float*)d_in[2];
  const float* im   = (const float*)d_in[3];
  const int* rgb    = (const int*)d_in[4];
  const int* iri    = (const int*)d_in[5];
  float* out = (float*)d_out;
  float* o0 = out;                 // Km  -> row_t (in place)
  float* o1 = out + 4000000;       // imb(bf16) -> KTm -> col_t (in place)
  float* o2 = out + 8000000;       // proto_v -> common_rm
  float* o3 = out + 12000000;      // proto_i -> specific_rm
  float* o4 = out + 16000000;      // E -> remain_rm
  float* o5 = out + 20000000;      // vmb(bf16) -> remain_col_rm
  char* sm = (char*)d_ws;
  float* ev   = (float*)(sm + 0);
  float* ei   = (float*)(sm + 8000);
  float* rv   = (float*)(sm + 16000);
  float* ri   = (float*)(sm + 24000);
  float* uvec = (float*)(sm + 32000);
  float* vvec = (float*)(sm + 40000);
  int* bar    = (int*)(sm + 48000);   // [0]=root, [32]=gen, [64+g*32]=groups
  float* rconf= (float*)(sm + 64000);
  float* cconf= (float*)(sm + 72000);
  int* rass = (int*)(sm + 80000);
  int* cass = (int*)(sm + 88000);
  int* cv   = (int*)(sm + 96000);
  int* ci   = (int*)(sm + 104000);
  int* ov   = (int*)(sm + 112000);
  int* oi   = (int*)(sm + 120000);
  int* curv = (int*)(sm + 128000);
  int* curi = (int*)(sm + 136000);
  int* ordv = (int*)(sm + 176000);
  int* ordi = (int*)(sm + 256000);
  unsigned short* vmb = (unsigned short*)o5;   // dead until k_post
  unsigned short* imb = (unsigned short*)o1;   // dead until k_tr (after gemm2)

  k_zero<<<47, 256, 0, stream>>>(cv, 12000, bar);  // cv..curi contiguous + barrier vars
  k_hist<<<157, 256, 0, stream>>>(rgb, iri, cv, ci);
  k_scan<<<1, 1024, 0, stream>>>(cv, ci, ov, oi);
  k_scatter<<<157, 256, 0, stream>>>(rgb, iri, ov, oi, curv, curi, ordv, ordi);
  k_class<<<2 * CN + 1000, 256, 0, stream>>>(visl, irl, cv, ci, ov, oi, ordv, ordi,
                                             o2, o3, ev, ei, vm, im, vmb, imb, rv, ri);
  k_prep<<<dim3(32, 32), 256, 0, stream>>>(o2, o3, ev, ei, cv, ci, o4);
  k_gemm2<<<dim3(16, 16), 256, 0, stream>>>(vmb, imb, rv, ri, o4, o0);
  k_tr<<<dim3(32, 32), 256, 0, stream>>>(o0, o1);
  k_sink<<<NBLK, 512, 0, stream>>>(o0, o1, cv, ci, uvec, vvec, o0, o1,
                                   rconf, cconf, rass, cass, bar);
  k_post<<<CN, 256, 0, stream>>>(o0, o1, cv, ci, rconf, cconf, rass, cass, o2, o3, o4, o5);
}